// Round 1
// baseline (13959.781 us; speedup 1.0000x reference)
//
#include <hip/hip_runtime.h>
#include <hip/hip_bf16.h>

typedef short short8 __attribute__((ext_vector_type(8)));
typedef float f32x4 __attribute__((ext_vector_type(4)));

constexpr int S = 256, B = 64, IN = 512, H = 1024;
constexpr int M = S * B;        // 16384
constexpr int NG = 4 * H;       // 4096

// ---------------- prep: fp32 -> bf16 ----------------
__global__ void f2b(const float* __restrict__ s, __hip_bfloat16* __restrict__ d, int n4) {
  int i = blockIdx.x * blockDim.x + threadIdx.x;
  if (i >= n4) return;
  float4 v = reinterpret_cast<const float4*>(s)[i];
  __hip_bfloat16 o[4] = {__float2bfloat16(v.x), __float2bfloat16(v.y),
                         __float2bfloat16(v.z), __float2bfloat16(v.w)};
  *reinterpret_cast<uint2*>(d + 4 * (size_t)i) = *reinterpret_cast<uint2*>(o);
}

__global__ void bias_k(const float* bx0, const float* bx1, const float* bx2, const float* bx3,
                       const float* bh0, const float* bh1, const float* bh2, const float* bh3,
                       float* bias) {
  int i = blockIdx.x * blockDim.x + threadIdx.x;
  if (i >= NG) return;
  int g = i >> 10, j = i & 1023;
  const float* bx = g == 0 ? bx0 : g == 1 ? bx1 : g == 2 ? bx2 : bx3;
  const float* bh = g == 0 ? bh0 : g == 1 ? bh1 : g == 2 ? bh2 : bh3;
  bias[i] = bx[j] + bh[j];
}

// ---------------- gx = x @ Wx^T + (bx+bh) ----------------
// A-frag: lane row = l&15 (m), k = kb*32 + (l>>4)*8 + i
// B-frag: lane col = l&15 (n), same k   (B[k][n] = Wx[n][k])
// C/D   : col = l&15 (n), row = (l>>4)*4 + r (m)
__global__ __launch_bounds__(256) void gx_gemm(const __hip_bfloat16* __restrict__ xb,
                                               const __hip_bfloat16* __restrict__ wxb,
                                               const float* __restrict__ bias,
                                               __hip_bfloat16* __restrict__ gx) {
  const int l = threadIdx.x & 63;
  const int w = threadIdx.x >> 6;
  const int m0 = blockIdx.y * 64 + w * 16;
  const int n0 = blockIdx.x * 64;
  const int cr = l & 15, kg = l >> 4;
  f32x4 acc[4] = {};
  const __hip_bfloat16* ap = xb + (size_t)(m0 + cr) * IN + kg * 8;
  const __hip_bfloat16* bp = wxb + (size_t)(n0 + cr) * IN + kg * 8;
  for (int k = 0; k < IN; k += 32) {
    short8 a = *reinterpret_cast<const short8*>(ap + k);
#pragma unroll
    for (int nt = 0; nt < 4; ++nt) {
      short8 b = *reinterpret_cast<const short8*>(bp + (size_t)nt * 16 * IN + k);
      acc[nt] = __builtin_amdgcn_mfma_f32_16x16x32_bf16(a, b, acc[nt], 0, 0, 0);
    }
  }
#pragma unroll
  for (int nt = 0; nt < 4; ++nt) {
    int n = n0 + nt * 16 + cr;
    float bv = bias[n];
#pragma unroll
    for (int r = 0; r < 4; ++r) {
      int m = m0 + kg * 4 + r;
      gx[(size_t)m * NG + n] = __float2bfloat16(acc[nt][r] + bv);
    }
  }
}

// ---------------- two-level grid barrier ----------------
__device__ inline void gbar(unsigned* bar, unsigned step) {
  __threadfence();
  __syncthreads();
  if (threadIdx.x == 0) {
    unsigned* gc = bar + (blockIdx.x >> 5) * 32;   // 8 group counters, 128B apart
    unsigned* root = bar + 8 * 32;
    unsigned* flag = bar + 9 * 32;
    unsigned prev = __hip_atomic_fetch_add(gc, 1u, __ATOMIC_ACQ_REL, __HIP_MEMORY_SCOPE_AGENT);
    if (prev == 31u) {
      __hip_atomic_store(gc, 0u, __ATOMIC_RELAXED, __HIP_MEMORY_SCOPE_AGENT);
      unsigned p2 = __hip_atomic_fetch_add(root, 1u, __ATOMIC_ACQ_REL, __HIP_MEMORY_SCOPE_AGENT);
      if (p2 == 7u) {
        __hip_atomic_store(root, 0u, __ATOMIC_RELAXED, __HIP_MEMORY_SCOPE_AGENT);
        __hip_atomic_store(flag, step, __ATOMIC_RELEASE, __HIP_MEMORY_SCOPE_AGENT);
        goto done;
      }
    }
    while (__hip_atomic_load(flag, __ATOMIC_RELAXED, __HIP_MEMORY_SCOPE_AGENT) < step)
      __builtin_amdgcn_s_sleep(2);
  done:;
  }
  __syncthreads();
  __threadfence();
}

// ---------------- persistent recurrence ----------------
// 256 blocks = 64 j-groups x 4 batch-groups; block = 4 waves; wave w = gate w.
// Per block output slice: 16 batches x 16 h-indices, all 4 gates. K = 1024.
__global__ __launch_bounds__(256, 1) void lstm_rec(const __hip_bfloat16* __restrict__ whb,
                                                   const __hip_bfloat16* __restrict__ gx,
                                                   __hip_bfloat16* __restrict__ hbuf,
                                                   float* __restrict__ out,
                                                   unsigned* __restrict__ bar) {
  __shared__ __align__(16) ushort Bf[4][32][64][8];  // 128 KB: Wh slice in B-frag order
  __shared__ float gt[4][16][16];
  __shared__ float ct[16][16];
  const int tid = threadIdx.x;
  const int l = tid & 63, w = tid >> 6;
  const int jg = blockIdx.x >> 2, bg = blockIdx.x & 3;
  const int j0 = jg * 16, b0 = bg * 16;

  // stage Wh slice into LDS, pre-swizzled to MFMA B-fragment order
  for (int idx = tid; idx < 4 * 32 * 64; idx += 256) {
    int g = idx >> 11, kb = (idx >> 6) & 31, ll = idx & 63;
    const __hip_bfloat16* src =
        whb + ((size_t)(g * H + j0 + (ll & 15))) * H + kb * 32 + (ll >> 4) * 8;
    *reinterpret_cast<uint4*>(&Bf[g][kb][ll][0]) = *reinterpret_cast<const uint4*>(src);
  }
  ct[tid & 15][tid >> 4] = 0.f;
  __syncthreads();

  const int cr = l & 15, kg = l >> 4;
  for (int t = 0; t < S; ++t) {
    const __hip_bfloat16* hsrc = hbuf + (size_t)(t & 1) * (B * H);
    __hip_bfloat16* hdst = hbuf + (size_t)((t + 1) & 1) * (B * H);

    f32x4 acc0 = {}, acc1 = {};
    const __hip_bfloat16* ap = hsrc + (size_t)(b0 + cr) * H + kg * 8;
#pragma unroll 4
    for (int kb = 0; kb < 32; kb += 2) {
      short8 a0 = *reinterpret_cast<const short8*>(ap + kb * 32);
      short8 bv0 = *reinterpret_cast<const short8*>(&Bf[w][kb][l][0]);
      acc0 = __builtin_amdgcn_mfma_f32_16x16x32_bf16(a0, bv0, acc0, 0, 0, 0);
      short8 a1 = *reinterpret_cast<const short8*>(ap + (kb + 1) * 32);
      short8 bv1 = *reinterpret_cast<const short8*>(&Bf[w][kb + 1][l][0]);
      acc1 = __builtin_amdgcn_mfma_f32_16x16x32_bf16(a1, bv1, acc1, 0, 0, 0);
    }
    f32x4 acc = acc0 + acc1;
#pragma unroll
    for (int r = 0; r < 4; ++r) gt[w][kg * 4 + r][cr] = acc[r];  // [gate][m][n]
    __syncthreads();

    {
      const int m = tid & 15, n = tid >> 4;
      const __hip_bfloat16* gxr = gx + ((size_t)(t * B + b0 + m)) * NG + j0 + n;
      float gf = gt[0][m][n] + __bfloat162float(gxr[0 * H]);
      float gi = gt[1][m][n] + __bfloat162float(gxr[1 * H]);
      float go = gt[2][m][n] + __bfloat162float(gxr[2 * H]);
      float gc = gt[3][m][n] + __bfloat162float(gxr[3 * H]);
      float f = 1.f / (1.f + __expf(-gf));
      float i_ = 1.f / (1.f + __expf(-gi));
      float o = 1.f / (1.f + __expf(-go));
      float cc = tanhf(gc);
      float cn = f * ct[m][n] + i_ * cc;
      float hn = o * tanhf(cn);
      ct[m][n] = cn;
      out[((size_t)(t * B + b0 + m)) * H + j0 + n] = hn;
      hdst[(size_t)(b0 + m) * H + j0 + n] = __float2bfloat16(hn);
      if (t == S - 1) {
        out[(size_t)S * B * H + (size_t)(b0 + m) * H + j0 + n] = hn;
        out[(size_t)S * B * H + (size_t)B * H + (size_t)(b0 + m) * H + j0 + n] = cn;
      }
    }
    if (t < S - 1) gbar(bar, (unsigned)(t + 1));
  }
}

extern "C" void kernel_launch(void* const* d_in, const int* in_sizes, int n_in,
                              void* d_out, int out_size, void* d_ws, size_t ws_size,
                              hipStream_t stream) {
  const float* x = (const float*)d_in[0];
  const float* Wx[4] = {(const float*)d_in[1], (const float*)d_in[3],
                        (const float*)d_in[5], (const float*)d_in[7]};
  const float* bx[4] = {(const float*)d_in[2], (const float*)d_in[4],
                        (const float*)d_in[6], (const float*)d_in[8]};
  const float* Wh[4] = {(const float*)d_in[9], (const float*)d_in[11],
                        (const float*)d_in[13], (const float*)d_in[15]};
  const float* bh[4] = {(const float*)d_in[10], (const float*)d_in[12],
                        (const float*)d_in[14], (const float*)d_in[16]};

  char* ws = (char*)d_ws;
  size_t o_bar = 0;
  size_t o_hbuf = 2048;
  size_t o_bias = o_hbuf + (size_t)2 * B * H * 2;   // hbuf: 256 KB
  size_t o_x = o_bias + (size_t)NG * 4;
  size_t o_wx = o_x + (size_t)M * IN * 2;
  size_t o_wh = o_wx + (size_t)NG * IN * 2;
  size_t o_gx = o_wh + (size_t)NG * H * 2;

  __hip_bfloat16* xb = (__hip_bfloat16*)(ws + o_x);
  __hip_bfloat16* wxb = (__hip_bfloat16*)(ws + o_wx);
  __hip_bfloat16* whb = (__hip_bfloat16*)(ws + o_wh);
  __hip_bfloat16* gxp = (__hip_bfloat16*)(ws + o_gx);
  __hip_bfloat16* hbufp = (__hip_bfloat16*)(ws + o_hbuf);
  float* biasp = (float*)(ws + o_bias);
  unsigned* barp = (unsigned*)(ws + o_bar);

  // zero barrier + h ping-pong buffers
  hipMemsetAsync(ws, 0, o_bias, stream);

  f2b<<<(M * IN / 4) / 256, 256, 0, stream>>>(x, xb, M * IN / 4);
  for (int g = 0; g < 4; ++g)
    f2b<<<(H * IN / 4) / 256, 256, 0, stream>>>(Wx[g], wxb + (size_t)g * H * IN, H * IN / 4);
  for (int g = 0; g < 4; ++g)
    f2b<<<(H * H / 4) / 256, 256, 0, stream>>>(Wh[g], whb + (size_t)g * H * H, H * H / 4);
  bias_k<<<NG / 256, 256, 0, stream>>>(bx[0], bx[1], bx[2], bx[3],
                                       bh[0], bh[1], bh[2], bh[3], biasp);

  dim3 gg(NG / 64, M / 64);
  gx_gemm<<<gg, 256, 0, stream>>>(xb, wxb, biasp, gxp);

  lstm_rec<<<256, 256, 0, stream>>>(whb, gxp, hbufp, (float*)d_out, barp);
}

// Round 2
// 3317.863 us; speedup vs baseline: 4.2075x; 4.2075x over previous
//
#include <hip/hip_runtime.h>
#include <hip/hip_bf16.h>

typedef short short8 __attribute__((ext_vector_type(8)));
typedef float f32x4 __attribute__((ext_vector_type(4)));

constexpr int S = 256, B = 64, IN = 512, H = 1024;
constexpr int M = S * B;        // 16384
constexpr int NG = 4 * H;       // 4096

// ---------------- prep: fp32 -> bf16 ----------------
__global__ void f2b(const float* __restrict__ s, __hip_bfloat16* __restrict__ d, int n4) {
  int i = blockIdx.x * blockDim.x + threadIdx.x;
  if (i >= n4) return;
  float4 v = reinterpret_cast<const float4*>(s)[i];
  __hip_bfloat16 o[4] = {__float2bfloat16(v.x), __float2bfloat16(v.y),
                         __float2bfloat16(v.z), __float2bfloat16(v.w)};
  *reinterpret_cast<uint2*>(d + 4 * (size_t)i) = *reinterpret_cast<uint2*>(o);
}

__global__ void bias_k(const float* bx0, const float* bx1, const float* bx2, const float* bx3,
                       const float* bh0, const float* bh1, const float* bh2, const float* bh3,
                       float* bias) {
  int i = blockIdx.x * blockDim.x + threadIdx.x;
  if (i >= NG) return;
  int g = i >> 10, j = i & 1023;
  const float* bx = g == 0 ? bx0 : g == 1 ? bx1 : g == 2 ? bx2 : bx3;
  const float* bh = g == 0 ? bh0 : g == 1 ? bh1 : g == 2 ? bh2 : bh3;
  bias[i] = bx[j] + bh[j];
}

// ---------------- gx = x @ Wx^T + (bx+bh), layout [t][b][j][gate] ----------------
__global__ __launch_bounds__(256) void gx_gemm(const __hip_bfloat16* __restrict__ xb,
                                               const __hip_bfloat16* __restrict__ wxb,
                                               const float* __restrict__ bias,
                                               __hip_bfloat16* __restrict__ gx) {
  const int l = threadIdx.x & 63;
  const int w = threadIdx.x >> 6;
  const int m0 = blockIdx.y * 64 + w * 16;
  const int n0 = blockIdx.x * 64;
  const int cr = l & 15, kg = l >> 4;
  f32x4 acc[4] = {};
  const __hip_bfloat16* ap = xb + (size_t)(m0 + cr) * IN + kg * 8;
  const __hip_bfloat16* bp = wxb + (size_t)(n0 + cr) * IN + kg * 8;
  for (int k = 0; k < IN; k += 32) {
    short8 a = *reinterpret_cast<const short8*>(ap + k);
#pragma unroll
    for (int nt = 0; nt < 4; ++nt) {
      short8 b = *reinterpret_cast<const short8*>(bp + (size_t)nt * 16 * IN + k);
      acc[nt] = __builtin_amdgcn_mfma_f32_16x16x32_bf16(a, b, acc[nt], 0, 0, 0);
    }
  }
#pragma unroll
  for (int nt = 0; nt < 4; ++nt) {
    int n = n0 + nt * 16 + cr;
    float bv = bias[n];
    int g = n >> 10, j = n & 1023;
#pragma unroll
    for (int r = 0; r < 4; ++r) {
      int m = m0 + kg * 4 + r;
      gx[((size_t)m * H + j) * 4 + g] = __float2bfloat16(acc[nt][r] + bv);
    }
  }
}

// ---------------- persistent recurrence ----------------
// 256 blocks = 64 j-groups x 4 batch-groups; block = 4 waves.
// Wave w computes partial gh over K in [w*256, w*256+256) for ALL 4 gates.
// Per block output slice: 16 batches x 16 h-indices x 4 gates. K = 1024.
__global__ __launch_bounds__(256, 1) void lstm_rec(const __hip_bfloat16* __restrict__ whb,
                                                   const __hip_bfloat16* __restrict__ gx,
                                                   __hip_bfloat16* __restrict__ hbuf,
                                                   float* __restrict__ out,
                                                   unsigned* __restrict__ bar) {
  __shared__ __align__(16) ushort Bf[4][32][64][8];   // 128 KB: Wh slice, B-frag order
  __shared__ __align__(16) float gt[4][4][16][20];    // [wave][gate][n=j][m=b], 20 KB padded
  const int tid = threadIdx.x;
  const int l = tid & 63, w = tid >> 6;
  const int jg = blockIdx.x >> 2, bg = blockIdx.x & 3;
  const int j0 = jg * 16, b0 = bg * 16;

  // stage Wh slice into LDS, pre-swizzled to MFMA B-fragment order
  for (int idx = tid; idx < 4 * 32 * 64; idx += 256) {
    int g = idx >> 11, kb = (idx >> 6) & 31, ll = idx & 63;
    const __hip_bfloat16* src =
        whb + ((size_t)(g * H + j0 + (ll & 15))) * H + kb * 32 + (ll >> 4) * 8;
    *reinterpret_cast<uint4*>(&Bf[g][kb][ll][0]) = *reinterpret_cast<const uint4*>(src);
  }
  __syncthreads();

  const int cr = l & 15, kg = l >> 4;
  const int kb0 = w * 8;
  const int bi = tid >> 4, j = tid & 15;   // gate-math mapping
  unsigned* myslot = bar + (size_t)blockIdx.x * 16;
  unsigned* pollslot = bar + (size_t)tid * 16;
  float c = 0.f;

  for (int t = 0; t < S; ++t) {
    const __hip_bfloat16* hsrc = hbuf + (size_t)(t & 1) * (B * H);
    __hip_bfloat16* hdst = hbuf + (size_t)((t + 1) & 1) * (B * H);

    if (t > 0) {
      // wait until every block has published h_t (per-block monotone counters)
      while (__hip_atomic_load(pollslot, __ATOMIC_RELAXED, __HIP_MEMORY_SCOPE_AGENT) <
             (unsigned)t)
        __builtin_amdgcn_s_sleep(1);
      if (tid == 0)
        (void)__hip_atomic_load(bar, __ATOMIC_ACQUIRE, __HIP_MEMORY_SCOPE_AGENT);
      __syncthreads();
    }

    // gx for this (t, bi, j): 4 gates contiguous, one 8B load (overlaps MFMA)
    const uint2 gq = *reinterpret_cast<const uint2*>(
        gx + (((size_t)(t * B + b0 + bi)) * H + j0 + j) * 4);

    // partial gh over this wave's K range
    f32x4 acc[4] = {};
    const __hip_bfloat16* ap = hsrc + (size_t)(b0 + cr) * H + kg * 8;
#pragma unroll
    for (int kk = 0; kk < 8; ++kk) {
      short8 a = *reinterpret_cast<const short8*>(ap + (kb0 + kk) * 32);
#pragma unroll
      for (int g = 0; g < 4; ++g) {
        short8 bv = *reinterpret_cast<const short8*>(&Bf[g][kb0 + kk][l][0]);
        acc[g] = __builtin_amdgcn_mfma_f32_16x16x32_bf16(a, bv, acc[g], 0, 0, 0);
      }
    }
#pragma unroll
    for (int g = 0; g < 4; ++g)
      *reinterpret_cast<f32x4*>(&gt[w][g][cr][kg * 4]) = acc[g];
    __syncthreads();

    // cross-wave K reduction + gates (thread owns (batch=bi, hidden=j))
    float sf = 0.f, si = 0.f, so = 0.f, sc = 0.f;
#pragma unroll
    for (int wv = 0; wv < 4; ++wv) {
      sf += gt[wv][0][j][bi];
      si += gt[wv][1][j][bi];
      so += gt[wv][2][j][bi];
      sc += gt[wv][3][j][bi];
    }
    float gf = sf + __uint_as_float(gq.x << 16);
    float gi = si + __uint_as_float(gq.x & 0xffff0000u);
    float go = so + __uint_as_float(gq.y << 16);
    float gc = sc + __uint_as_float(gq.y & 0xffff0000u);
    float f = 1.f / (1.f + __expf(-gf));
    float i_ = 1.f / (1.f + __expf(-gi));
    float o = 1.f / (1.f + __expf(-go));
    float cn = f * c + i_ * tanhf(gc);
    float hn = o * tanhf(cn);
    c = cn;

    out[((size_t)(t * B + b0 + bi)) * H + j0 + j] = hn;
    hdst[(size_t)(b0 + bi) * H + j0 + j] = __float2bfloat16(hn);
    if (t == S - 1) {
      out[(size_t)S * B * H + (size_t)(b0 + bi) * H + j0 + j] = hn;
      out[(size_t)S * B * H + (size_t)B * H + (size_t)(b0 + bi) * H + j0 + j] = cn;
    }
    __syncthreads();  // drains all waves' global stores (vmcnt0 before s_barrier)
    if (t < S - 1 && tid == 0)
      __hip_atomic_store(myslot, (unsigned)(t + 1), __ATOMIC_RELEASE,
                         __HIP_MEMORY_SCOPE_AGENT);
  }
}

extern "C" void kernel_launch(void* const* d_in, const int* in_sizes, int n_in,
                              void* d_out, int out_size, void* d_ws, size_t ws_size,
                              hipStream_t stream) {
  const float* x = (const float*)d_in[0];
  const float* Wx[4] = {(const float*)d_in[1], (const float*)d_in[3],
                        (const float*)d_in[5], (const float*)d_in[7]};
  const float* bx[4] = {(const float*)d_in[2], (const float*)d_in[4],
                        (const float*)d_in[6], (const float*)d_in[8]};
  const float* Wh[4] = {(const float*)d_in[9], (const float*)d_in[11],
                        (const float*)d_in[13], (const float*)d_in[15]};
  const float* bh[4] = {(const float*)d_in[10], (const float*)d_in[12],
                        (const float*)d_in[14], (const float*)d_in[16]};

  char* ws = (char*)d_ws;
  size_t o_bar = 0;                                   // 256 slots x 64B = 16 KB
  size_t o_hbuf = 16384;
  size_t o_bias = o_hbuf + (size_t)2 * B * H * 2;     // hbuf: 256 KB
  size_t o_x = o_bias + (size_t)NG * 4;
  size_t o_wx = o_x + (size_t)M * IN * 2;
  size_t o_wh = o_wx + (size_t)NG * IN * 2;
  size_t o_gx = o_wh + (size_t)NG * H * 2;

  __hip_bfloat16* xb = (__hip_bfloat16*)(ws + o_x);
  __hip_bfloat16* wxb = (__hip_bfloat16*)(ws + o_wx);
  __hip_bfloat16* whb = (__hip_bfloat16*)(ws + o_wh);
  __hip_bfloat16* gxp = (__hip_bfloat16*)(ws + o_gx);
  __hip_bfloat16* hbufp = (__hip_bfloat16*)(ws + o_hbuf);
  float* biasp = (float*)(ws + o_bias);
  unsigned* barp = (unsigned*)(ws + o_bar);

  // zero barrier slots + h ping-pong buffers (runs inside the graph every replay)
  hipMemsetAsync(ws, 0, o_bias, stream);

  f2b<<<(M * IN / 4) / 256, 256, 0, stream>>>(x, xb, M * IN / 4);
  for (int g = 0; g < 4; ++g)
    f2b<<<(H * IN / 4) / 256, 256, 0, stream>>>(Wx[g], wxb + (size_t)g * H * IN, H * IN / 4);
  for (int g = 0; g < 4; ++g)
    f2b<<<(H * H / 4) / 256, 256, 0, stream>>>(Wh[g], whb + (size_t)g * H * H, H * H / 4);
  bias_k<<<NG / 256, 256, 0, stream>>>(bx[0], bx[1], bx[2], bx[3],
                                       bh[0], bh[1], bh[2], bh[3], biasp);

  dim3 gg(NG / 64, M / 64);
  gx_gemm<<<gg, 256, 0, stream>>>(xb, wxb, biasp, gxp);

  lstm_rec<<<256, 256, 0, stream>>>(whb, gxp, hbufp, (float*)d_out, barp);
}

// Round 3
// 1642.930 us; speedup vs baseline: 8.4969x; 2.0195x over previous
//
#include <hip/hip_runtime.h>
#include <hip/hip_bf16.h>

typedef short short8 __attribute__((ext_vector_type(8)));
typedef float f32x4 __attribute__((ext_vector_type(4)));
typedef unsigned long long u64;

constexpr int S = 256, B = 64, IN = 512, H = 1024;
constexpr int M = S * B;        // 16384
constexpr int NG = 4 * H;       // 4096

// ---------------- prep: fp32 -> bf16 ----------------
__global__ void f2b(const float* __restrict__ s, __hip_bfloat16* __restrict__ d, int n4) {
  int i = blockIdx.x * blockDim.x + threadIdx.x;
  if (i >= n4) return;
  float4 v = reinterpret_cast<const float4*>(s)[i];
  __hip_bfloat16 o[4] = {__float2bfloat16(v.x), __float2bfloat16(v.y),
                         __float2bfloat16(v.z), __float2bfloat16(v.w)};
  *reinterpret_cast<uint2*>(d + 4 * (size_t)i) = *reinterpret_cast<uint2*>(o);
}

__global__ void bias_k(const float* bx0, const float* bx1, const float* bx2, const float* bx3,
                       const float* bh0, const float* bh1, const float* bh2, const float* bh3,
                       float* bias) {
  int i = blockIdx.x * blockDim.x + threadIdx.x;
  if (i >= NG) return;
  int g = i >> 10, j = i & 1023;
  const float* bx = g == 0 ? bx0 : g == 1 ? bx1 : g == 2 ? bx2 : bx3;
  const float* bh = g == 0 ? bh0 : g == 1 ? bh1 : g == 2 ? bh2 : bh3;
  bias[i] = bx[j] + bh[j];
}

// ---------------- gx = x @ Wx^T + (bx+bh), layout [t][b][j][gate] ----------------
__global__ __launch_bounds__(256) void gx_gemm(const __hip_bfloat16* __restrict__ xb,
                                               const __hip_bfloat16* __restrict__ wxb,
                                               const float* __restrict__ bias,
                                               __hip_bfloat16* __restrict__ gx) {
  const int l = threadIdx.x & 63;
  const int w = threadIdx.x >> 6;
  const int m0 = blockIdx.y * 64 + w * 16;
  const int n0 = blockIdx.x * 64;
  const int cr = l & 15, kg = l >> 4;
  f32x4 acc[4] = {};
  const __hip_bfloat16* ap = xb + (size_t)(m0 + cr) * IN + kg * 8;
  const __hip_bfloat16* bp = wxb + (size_t)(n0 + cr) * IN + kg * 8;
  for (int k = 0; k < IN; k += 32) {
    short8 a = *reinterpret_cast<const short8*>(ap + k);
#pragma unroll
    for (int nt = 0; nt < 4; ++nt) {
      short8 b = *reinterpret_cast<const short8*>(bp + (size_t)nt * 16 * IN + k);
      acc[nt] = __builtin_amdgcn_mfma_f32_16x16x32_bf16(a, b, acc[nt], 0, 0, 0);
    }
  }
#pragma unroll
  for (int nt = 0; nt < 4; ++nt) {
    int n = n0 + nt * 16 + cr;
    float bv = bias[n];
    int g = n >> 10, j = n & 1023;
#pragma unroll
    for (int r = 0; r < 4; ++r) {
      int m = m0 + kg * 4 + r;
      gx[((size_t)m * H + j) * 4 + g] = __float2bfloat16(acc[nt][r] + bv);
    }
  }
}

__device__ __forceinline__ u64 ldg_agent(const u64* p) {
  return __hip_atomic_load(p, __ATOMIC_RELAXED, __HIP_MEMORY_SCOPE_AGENT);
}
__device__ __forceinline__ void stg_agent(u64* p, u64 v) {
  __hip_atomic_store(p, v, __ATOMIC_RELAXED, __HIP_MEMORY_SCOPE_AGENT);
}

// ---------------- persistent recurrence ----------------
// 256 blocks = 64 j-groups x 4 batch-groups; block = 4 waves.
// Wave w: partial gh over K in [w*256, w*256+256) for all 4 gates.
// All cross-block traffic (h, flags) via relaxed agent atomics (sc1, L3-coherent)
// -> NO wbl2/inv cache maintenance in the loop.
__global__ __launch_bounds__(256, 1) void lstm_rec(const __hip_bfloat16* __restrict__ whb,
                                                   const __hip_bfloat16* __restrict__ gx,
                                                   __hip_bfloat16* __restrict__ hbuf,
                                                   float* __restrict__ out,
                                                   unsigned* __restrict__ bar) {
  __shared__ __align__(16) ushort Bf[4][32][64][8];   // 128 KB: Wh slice, B-frag order
  __shared__ __align__(16) float gt[4][4][16][20];    // [wave][gate][n=j][m=b]
  const int tid = threadIdx.x;
  const int l = tid & 63, w = tid >> 6;
  const int jg = blockIdx.x >> 2, bg = blockIdx.x & 3;
  const int j0 = jg * 16, b0 = bg * 16;

  // stage Wh slice into LDS, pre-swizzled to MFMA B-fragment order
  for (int idx = tid; idx < 4 * 32 * 64; idx += 256) {
    int g = idx >> 11, kb = (idx >> 6) & 31, ll = idx & 63;
    const __hip_bfloat16* src =
        whb + ((size_t)(g * H + j0 + (ll & 15))) * H + kb * 32 + (ll >> 4) * 8;
    *reinterpret_cast<uint4*>(&Bf[g][kb][ll][0]) = *reinterpret_cast<const uint4*>(src);
  }
  __syncthreads();

  const int cr = l & 15, kg = l >> 4;
  const int kb0 = w * 8;
  const int bi = tid >> 4, j = tid & 15;   // gate-math mapping
  unsigned* myslot = bar + (size_t)blockIdx.x * 16;
  unsigned* pollslot = bar + (size_t)tid * 16;
  float c = 0.f;

  for (int t = 0; t < S; ++t) {
    const __hip_bfloat16* hsrc = hbuf + (size_t)(t & 1) * (B * H);
    __hip_bfloat16* hdst = hbuf + (size_t)((t + 1) & 1) * (B * H);

    // prefetch gx for this (t, bi, j): independent of h -> issue before the wait
    const uint2 gq = *reinterpret_cast<const uint2*>(
        gx + (((size_t)(t * B + b0 + bi)) * H + j0 + j) * 4);

    if (t > 0) {
      // wait until every block has published h_t (per-block monotone counters)
      while (__hip_atomic_load(pollslot, __ATOMIC_RELAXED, __HIP_MEMORY_SCOPE_AGENT) <
             (unsigned)t)
        __builtin_amdgcn_s_sleep(1);
      asm volatile("" ::: "memory");  // no hoisting of h loads above the poll
    }

    // load this thread's A-fragments (h rows) via L2-bypassing 8B atomics
    u64 ha[16];
    {
      const u64* hp = reinterpret_cast<const u64*>(hsrc + (size_t)(b0 + cr) * H) + kg * 2;
#pragma unroll
      for (int kk = 0; kk < 8; ++kk) {
        ha[2 * kk] = ldg_agent(hp + (size_t)(kb0 + kk) * 8);
        ha[2 * kk + 1] = ldg_agent(hp + (size_t)(kb0 + kk) * 8 + 1);
      }
    }

    // partial gh over this wave's K range
    f32x4 acc[4] = {};
#pragma unroll
    for (int kk = 0; kk < 8; ++kk) {
      union { u64 q[2]; short8 s; } ua;
      ua.q[0] = ha[2 * kk];
      ua.q[1] = ha[2 * kk + 1];
#pragma unroll
      for (int g = 0; g < 4; ++g) {
        short8 bv = *reinterpret_cast<const short8*>(&Bf[g][kb0 + kk][l][0]);
        acc[g] = __builtin_amdgcn_mfma_f32_16x16x32_bf16(ua.s, bv, acc[g], 0, 0, 0);
      }
    }
#pragma unroll
    for (int g = 0; g < 4; ++g)
      *reinterpret_cast<f32x4*>(&gt[w][g][cr][kg * 4]) = acc[g];
    __syncthreads();

    // cross-wave K reduction + gates (thread owns (batch=bi, hidden=j))
    float sf = 0.f, si = 0.f, so = 0.f, sc = 0.f;
#pragma unroll
    for (int wv = 0; wv < 4; ++wv) {
      sf += gt[wv][0][j][bi];
      si += gt[wv][1][j][bi];
      so += gt[wv][2][j][bi];
      sc += gt[wv][3][j][bi];
    }
    float gf = sf + __uint_as_float(gq.x << 16);
    float gi = si + __uint_as_float(gq.x & 0xffff0000u);
    float go = so + __uint_as_float(gq.y << 16);
    float gc = sc + __uint_as_float(gq.y & 0xffff0000u);
    float f = 1.f / (1.f + __expf(-gf));
    float i_ = 1.f / (1.f + __expf(-gi));
    float o = 1.f / (1.f + __expf(-go));
    float cn = f * c + i_ * tanhf(gc);
    float hn = o * tanhf(cn);
    c = cn;

    out[((size_t)(t * B + b0 + bi)) * H + j0 + j] = hn;
    if (t == S - 1) {
      out[(size_t)S * B * H + (size_t)(b0 + bi) * H + j0 + j] = hn;
      out[(size_t)S * B * H + (size_t)B * H + (size_t)(b0 + bi) * H + j0 + j] = cn;
    }

    // pack 4 consecutive j's bf16 into one u64 via shfl, store L2-bypassing
    {
      unsigned hs16 = (unsigned)__bfloat16_as_ushort(__float2bfloat16(hn));
      unsigned p1 = (hs16 & 0xffffu) | ((unsigned)__shfl_xor((int)hs16, 1) << 16);
      unsigned p2 = (unsigned)__shfl_xor((int)p1, 2);
      if ((j & 3) == 0) {
        u64 pk = (u64)p1 | ((u64)p2 << 32);
        stg_agent(reinterpret_cast<u64*>(hdst + (size_t)(b0 + bi) * H + j0 + j), pk);
      }
    }

    __syncthreads();  // each thread drains vmcnt(0) before barrier -> h stores at L3
    asm volatile("" ::: "memory");
    if (t < S - 1 && tid == 0)
      __hip_atomic_store(myslot, (unsigned)(t + 1), __ATOMIC_RELAXED,
                         __HIP_MEMORY_SCOPE_AGENT);
  }
}

extern "C" void kernel_launch(void* const* d_in, const int* in_sizes, int n_in,
                              void* d_out, int out_size, void* d_ws, size_t ws_size,
                              hipStream_t stream) {
  const float* x = (const float*)d_in[0];
  const float* Wx[4] = {(const float*)d_in[1], (const float*)d_in[3],
                        (const float*)d_in[5], (const float*)d_in[7]};
  const float* bx[4] = {(const float*)d_in[2], (const float*)d_in[4],
                        (const float*)d_in[6], (const float*)d_in[8]};
  const float* Wh[4] = {(const float*)d_in[9], (const float*)d_in[11],
                        (const float*)d_in[13], (const float*)d_in[15]};
  const float* bh[4] = {(const float*)d_in[10], (const float*)d_in[12],
                        (const float*)d_in[14], (const float*)d_in[16]};

  char* ws = (char*)d_ws;
  size_t o_bar = 0;                                   // 256 slots x 64B = 16 KB
  size_t o_hbuf = 16384;
  size_t o_bias = o_hbuf + (size_t)2 * B * H * 2;     // hbuf: 256 KB
  size_t o_x = o_bias + (size_t)NG * 4;
  size_t o_wx = o_x + (size_t)M * IN * 2;
  size_t o_wh = o_wx + (size_t)NG * IN * 2;
  size_t o_gx = o_wh + (size_t)NG * H * 2;

  __hip_bfloat16* xb = (__hip_bfloat16*)(ws + o_x);
  __hip_bfloat16* wxb = (__hip_bfloat16*)(ws + o_wx);
  __hip_bfloat16* whb = (__hip_bfloat16*)(ws + o_wh);
  __hip_bfloat16* gxp = (__hip_bfloat16*)(ws + o_gx);
  __hip_bfloat16* hbufp = (__hip_bfloat16*)(ws + o_hbuf);
  float* biasp = (float*)(ws + o_bias);
  unsigned* barp = (unsigned*)(ws + o_bar);

  // zero barrier slots + h ping-pong buffers (runs inside the graph every replay)
  hipMemsetAsync(ws, 0, o_bias, stream);

  f2b<<<(M * IN / 4) / 256, 256, 0, stream>>>(x, xb, M * IN / 4);
  for (int g = 0; g < 4; ++g)
    f2b<<<(H * IN / 4) / 256, 256, 0, stream>>>(Wx[g], wxb + (size_t)g * H * IN, H * IN / 4);
  for (int g = 0; g < 4; ++g)
    f2b<<<(H * H / 4) / 256, 256, 0, stream>>>(Wh[g], whb + (size_t)g * H * H, H * H / 4);
  bias_k<<<NG / 256, 256, 0, stream>>>(bx[0], bx[1], bx[2], bx[3],
                                       bh[0], bh[1], bh[2], bh[3], biasp);

  dim3 gg(NG / 64, M / 64);
  gx_gemm<<<gg, 256, 0, stream>>>(xb, wxb, biasp, gxp);

  lstm_rec<<<256, 256, 0, stream>>>(whb, gxp, hbufp, (float*)d_out, barp);
}